// Round 1
// baseline (143.689 us; speedup 1.0000x reference)
//
#include <hip/hip_runtime.h>

#define N_NODES 5000
#define N_EDGES 40000
#define ROWS 48            // BATCH * SEQ = 4*12
#define FIN 64
#define FOUT 64
#define NODE_ELEMS (ROWS * FIN)     // 3072 floats per node
#define NODE_VEC4  (NODE_ELEMS / 4) // 768 float4 per node
#define OUT_ROW 128                 // concat(FOUT, FOUT)
#define NODE_OUT (ROWS * OUT_ROW)   // 6144 floats per node output

__global__ void zero_counts_kernel(int* __restrict__ counts) {
    int i = blockIdx.x * 256 + threadIdx.x;
    if (i < N_NODES) counts[i] = 0;
}

__global__ void hist_kernel(const int* __restrict__ edges_dst, int* __restrict__ counts) {
    int e = blockIdx.x * 256 + threadIdx.x;
    if (e < N_EDGES) atomicAdd(&counts[edges_dst[e]], 1);
}

// Exclusive scan of counts -> offsets[0..N_NODES], also copies to cursor.
__global__ void scan_kernel(const int* __restrict__ counts,
                            int* __restrict__ offsets,
                            int* __restrict__ cursor) {
    __shared__ int buf[1024];
    __shared__ int carry_s;
    int tid = threadIdx.x;
    if (tid == 0) carry_s = 0;
    __syncthreads();
    for (int base = 0; base < N_NODES; base += 1024) {
        int i = base + tid;
        int v = (i < N_NODES) ? counts[i] : 0;
        buf[tid] = v;
        __syncthreads();
        int x = v;
        for (int off = 1; off < 1024; off <<= 1) {
            int t = (tid >= off) ? buf[tid - off] : 0;
            __syncthreads();
            x += t;
            buf[tid] = x;
            __syncthreads();
        }
        int c = carry_s;
        if (i < N_NODES) {
            int excl = c + x - v;
            offsets[i] = excl;
            cursor[i] = excl;
        }
        __syncthreads();
        if (tid == 0) carry_s = c + buf[1023];
        __syncthreads();
    }
    if (threadIdx.x == 0) offsets[N_NODES] = carry_s;
}

__global__ void scatter_kernel(const int* __restrict__ edges_dst,
                               const int* __restrict__ edges_src,
                               int* __restrict__ cursor,
                               int* __restrict__ csr_src) {
    int e = blockIdx.x * 256 + threadIdx.x;
    if (e < N_EDGES) {
        int d = edges_dst[e];
        int p = atomicAdd(&cursor[d], 1);
        csr_src[p] = edges_src[e];
    }
}

__global__ __launch_bounds__(256) void main_kernel(
    const float* __restrict__ feat,
    const float* __restrict__ W,
    const int* __restrict__ offsets,
    const int* __restrict__ csr_src,
    float* __restrict__ out) {
    __shared__ __align__(16) float lds_w[FIN * FOUT];   // 16 KB, [k][j]
    __shared__ __align__(16) float lds_t[NODE_ELEMS];   // 12 KB, [r][k]

    const int n = blockIdx.x;
    const int tid = threadIdx.x;

    // stage W
    {
        const float4* w4 = (const float4*)W;
        float4* l4 = (float4*)lds_w;
        #pragma unroll
        for (int i = 0; i < 4; ++i) l4[tid + i * 256] = w4[tid + i * 256];
    }
    // stage this node's feature tile
    {
        const float4* f4 = (const float4*)(feat + (size_t)n * NODE_ELEMS);
        float4* l4 = (float4*)lds_t;
        #pragma unroll
        for (int i = 0; i < 3; ++i) l4[tid + i * 256] = f4[tid + i * 256];
    }
    __syncthreads();

    // each thread owns one output column j across all its 12 output elements
    const int j = tid & 63;
    float wcol[64];
    #pragma unroll
    for (int k = 0; k < 64; ++k) wcol[k] = lds_w[k * 64 + j];

    float* outn = out + (size_t)n * NODE_OUT;

    // left half: relu(F[n] @ W)
    #pragma unroll
    for (int i = 0; i < 12; ++i) {
        int elem = tid + i * 256;
        int r = elem >> 6;
        const float4* m4 = (const float4*)(lds_t + r * 64);  // broadcast reads
        float s = 0.f;
        #pragma unroll
        for (int k4 = 0; k4 < 16; ++k4) {
            float4 m = m4[k4];
            s += m.x * wcol[4 * k4 + 0] + m.y * wcol[4 * k4 + 1] +
                 m.z * wcol[4 * k4 + 2] + m.w * wcol[4 * k4 + 3];
        }
        outn[r * OUT_ROW + j] = fmaxf(s, 0.f);
    }

    // gather neighbor features (coalesced float4 per edge)
    const int e0 = offsets[n], e1 = offsets[n + 1];
    float4 acc[3];
    #pragma unroll
    for (int i = 0; i < 3; ++i) acc[i] = make_float4(0.f, 0.f, 0.f, 0.f);
    for (int e = e0; e < e1; ++e) {
        int src = csr_src[e];
        const float4* f4 = (const float4*)(feat + (size_t)src * NODE_ELEMS);
        #pragma unroll
        for (int i = 0; i < 3; ++i) {
            float4 v = f4[tid + i * 256];
            acc[i].x += v.x; acc[i].y += v.y; acc[i].z += v.z; acc[i].w += v.w;
        }
    }
    const float inv = 1.0f / (float)((e1 - e0) > 1 ? (e1 - e0) : 1);

    __syncthreads();  // left matmul done reading lds_t
    {
        float4* l4 = (float4*)lds_t;
        #pragma unroll
        for (int i = 0; i < 3; ++i) {
            float4 a = acc[i];
            a.x *= inv; a.y *= inv; a.z *= inv; a.w *= inv;
            l4[tid + i * 256] = a;
        }
    }
    __syncthreads();

    // right half: relu(mean @ W)
    #pragma unroll
    for (int i = 0; i < 12; ++i) {
        int elem = tid + i * 256;
        int r = elem >> 6;
        const float4* m4 = (const float4*)(lds_t + r * 64);
        float s = 0.f;
        #pragma unroll
        for (int k4 = 0; k4 < 16; ++k4) {
            float4 m = m4[k4];
            s += m.x * wcol[4 * k4 + 0] + m.y * wcol[4 * k4 + 1] +
                 m.z * wcol[4 * k4 + 2] + m.w * wcol[4 * k4 + 3];
        }
        outn[r * OUT_ROW + 64 + j] = fmaxf(s, 0.f);
    }
}

extern "C" void kernel_launch(void* const* d_in, const int* in_sizes, int n_in,
                              void* d_out, int out_size, void* d_ws, size_t ws_size,
                              hipStream_t stream) {
    const float* feat = (const float*)d_in[0];
    const float* W    = (const float*)d_in[1];
    const int* edst   = (const int*)d_in[2];
    const int* esrc   = (const int*)d_in[3];
    float* out = (float*)d_out;

    int* counts  = (int*)d_ws;
    int* offsets = counts + N_NODES;        // N_NODES + 1 ints
    int* cursor  = offsets + N_NODES + 1;
    int* csr_src = cursor + N_NODES;        // N_EDGES ints

    zero_counts_kernel<<<(N_NODES + 255) / 256, 256, 0, stream>>>(counts);
    hist_kernel<<<(N_EDGES + 255) / 256, 256, 0, stream>>>(edst, counts);
    scan_kernel<<<1, 1024, 0, stream>>>(counts, offsets, cursor);
    scatter_kernel<<<(N_EDGES + 255) / 256, 256, 0, stream>>>(edst, esrc, cursor, csr_src);
    main_kernel<<<N_NODES, 256, 0, stream>>>(feat, W, offsets, csr_src, out);
}

// Round 2
// 107.684 us; speedup vs baseline: 1.3344x; 1.3344x over previous
//
#include <hip/hip_runtime.h>

#define N_NODES 5000
#define N_EDGES 40000
#define ROWS 48            // BATCH * SEQ = 4*12
#define FIN 64
#define FOUT 64
#define NODE_ELEMS (ROWS * FIN)     // 3072
#define OUT_ROW 128                 // concat(FOUT, FOUT)
#define NODE_OUT (ROWS * OUT_ROW)   // 6144

// ---------------- CSR build ----------------

__global__ void zero_counts_kernel(int* __restrict__ counts) {
    int i = blockIdx.x * 256 + threadIdx.x;
    if (i < N_NODES) counts[i] = 0;
}

__global__ void hist_kernel(const int* __restrict__ edges_dst, int* __restrict__ counts) {
    int e = blockIdx.x * 256 + threadIdx.x;
    if (e < N_EDGES) atomicAdd(&counts[edges_dst[e]], 1);
}

__global__ void scan_kernel(const int* __restrict__ counts,
                            int* __restrict__ offsets,
                            int* __restrict__ cursor) {
    __shared__ int buf[1024];
    __shared__ int carry_s;
    int tid = threadIdx.x;
    if (tid == 0) carry_s = 0;
    __syncthreads();
    for (int base = 0; base < N_NODES; base += 1024) {
        int i = base + tid;
        int v = (i < N_NODES) ? counts[i] : 0;
        buf[tid] = v;
        __syncthreads();
        int x = v;
        for (int off = 1; off < 1024; off <<= 1) {
            int t = (tid >= off) ? buf[tid - off] : 0;
            __syncthreads();
            x += t;
            buf[tid] = x;
            __syncthreads();
        }
        int c = carry_s;
        if (i < N_NODES) {
            int excl = c + x - v;
            offsets[i] = excl;
            cursor[i] = excl;
        }
        __syncthreads();
        if (tid == 0) carry_s = c + buf[1023];
        __syncthreads();
    }
    if (threadIdx.x == 0) offsets[N_NODES] = carry_s;
}

__global__ void scatter_kernel(const int* __restrict__ edges_dst,
                               const int* __restrict__ edges_src,
                               int* __restrict__ cursor,
                               int* __restrict__ csr_src) {
    int e = blockIdx.x * 256 + threadIdx.x;
    if (e < N_EDGES) {
        int d = edges_dst[e];
        int p = atomicAdd(&cursor[d], 1);
        csr_src[p] = edges_src[e];
    }
}

// ---------------- Kernel A: Q = F@W, left half = relu(Q), Q -> bf16 ws ----------------

__global__ __launch_bounds__(256) void matmul_kernel(
    const float* __restrict__ feat,
    const float* __restrict__ W,
    float* __restrict__ out,
    unsigned short* __restrict__ Q) {
    __shared__ __align__(16) float lds[FIN * FOUT];  // 16 KB, reused: W then features

    const int n = blockIdx.x;
    const int tid = threadIdx.x;
    const int j = tid & 63;

    // stage W
    {
        const float4* w4 = (const float4*)W;
        float4* l4 = (float4*)lds;
        #pragma unroll
        for (int i = 0; i < 4; ++i) l4[tid + i * 256] = w4[tid + i * 256];
    }
    __syncthreads();
    float wcol[64];
    #pragma unroll
    for (int k = 0; k < 64; ++k) wcol[k] = lds[k * 64 + j];
    __syncthreads();
    // stage this node's feature tile (reuse same LDS)
    {
        const float4* f4 = (const float4*)(feat + (size_t)n * NODE_ELEMS);
        float4* l4 = (float4*)lds;
        #pragma unroll
        for (int i = 0; i < 3; ++i) l4[tid + i * 256] = f4[tid + i * 256];
    }
    __syncthreads();

    float* outn = out + (size_t)n * NODE_OUT;
    unsigned short* qn = Q + (size_t)n * NODE_ELEMS;

    #pragma unroll
    for (int i = 0; i < 12; ++i) {
        int r = (tid + i * 256) >> 6;                    // uniform per wave
        const float4* m4 = (const float4*)(lds + r * 64);
        float s = 0.f;
        #pragma unroll
        for (int k4 = 0; k4 < 16; ++k4) {
            float4 m = m4[k4];
            s = fmaf(m.x, wcol[4 * k4 + 0], s);
            s = fmaf(m.y, wcol[4 * k4 + 1], s);
            s = fmaf(m.z, wcol[4 * k4 + 2], s);
            s = fmaf(m.w, wcol[4 * k4 + 3], s);
        }
        outn[r * OUT_ROW + j] = fmaxf(s, 0.f);
        unsigned int u = __float_as_uint(s);             // f32 -> bf16 RNE
        u += 0x7fffu + ((u >> 16) & 1u);
        qn[r * FIN + j] = (unsigned short)(u >> 16);
    }
}

// ---------------- Kernel B: right half = relu(mean_src Q_bf16[src]) ----------------

__device__ __forceinline__ void acc_u4(float* a, uint4 v) {
    a[0] += __uint_as_float(v.x << 16); a[1] += __uint_as_float(v.x & 0xffff0000u);
    a[2] += __uint_as_float(v.y << 16); a[3] += __uint_as_float(v.y & 0xffff0000u);
    a[4] += __uint_as_float(v.z << 16); a[5] += __uint_as_float(v.z & 0xffff0000u);
    a[6] += __uint_as_float(v.w << 16); a[7] += __uint_as_float(v.w & 0xffff0000u);
}
__device__ __forceinline__ void acc_u2(float* a, uint2 v) {
    a[0] += __uint_as_float(v.x << 16); a[1] += __uint_as_float(v.x & 0xffff0000u);
    a[2] += __uint_as_float(v.y << 16); a[3] += __uint_as_float(v.y & 0xffff0000u);
}

__global__ __launch_bounds__(256) void gather_kernel(
    const unsigned short* __restrict__ Q,
    const int* __restrict__ offsets,
    const int* __restrict__ csr_src,
    float* __restrict__ out) {
    const int n = blockIdx.x;
    const int tid = threadIdx.x;
    const int e0 = offsets[n];
    const int cnt = offsets[n + 1] - e0;

    // thread owns elems [tid*8, tid*8+8) and [2048 + tid*4, +4)
    float acc[12];
    #pragma unroll
    for (int i = 0; i < 12; ++i) acc[i] = 0.f;

    int e = 0;
    for (; e + 2 <= cnt; e += 2) {
        int s0 = csr_src[e0 + e];
        int s1 = csr_src[e0 + e + 1];
        const unsigned short* q0 = Q + (size_t)s0 * NODE_ELEMS;
        const unsigned short* q1 = Q + (size_t)s1 * NODE_ELEMS;
        uint4 a0 = *(const uint4*)(q0 + tid * 8);
        uint2 b0 = *(const uint2*)(q0 + 2048 + tid * 4);
        uint4 a1 = *(const uint4*)(q1 + tid * 8);
        uint2 b1 = *(const uint2*)(q1 + 2048 + tid * 4);
        acc_u4(acc, a0);  acc_u2(acc + 8, b0);
        acc_u4(acc, a1);  acc_u2(acc + 8, b1);
    }
    if (e < cnt) {
        int s0 = csr_src[e0 + e];
        const unsigned short* q0 = Q + (size_t)s0 * NODE_ELEMS;
        uint4 a0 = *(const uint4*)(q0 + tid * 8);
        uint2 b0 = *(const uint2*)(q0 + 2048 + tid * 4);
        acc_u4(acc, a0);  acc_u2(acc + 8, b0);
    }

    const float inv = 1.0f / (float)(cnt > 1 ? cnt : 1);
    float* outn = out + (size_t)n * NODE_OUT;

    // elems 0..2047: m = tid*8 -> row tid>>3, col (tid&7)*8
    {
        int r = tid >> 3, c = (tid & 7) * 8;
        float* p = outn + r * OUT_ROW + 64 + c;
        float4 v0 = make_float4(fmaxf(acc[0] * inv, 0.f), fmaxf(acc[1] * inv, 0.f),
                                fmaxf(acc[2] * inv, 0.f), fmaxf(acc[3] * inv, 0.f));
        float4 v1 = make_float4(fmaxf(acc[4] * inv, 0.f), fmaxf(acc[5] * inv, 0.f),
                                fmaxf(acc[6] * inv, 0.f), fmaxf(acc[7] * inv, 0.f));
        *(float4*)(p) = v0;
        *(float4*)(p + 4) = v1;
    }
    // elems 2048..3071: m = 2048 + tid*4 -> row 32 + (tid>>4), col (tid&15)*4
    {
        int r = 32 + (tid >> 4), c = (tid & 15) * 4;
        float* p = outn + r * OUT_ROW + 64 + c;
        float4 v = make_float4(fmaxf(acc[8] * inv, 0.f), fmaxf(acc[9] * inv, 0.f),
                               fmaxf(acc[10] * inv, 0.f), fmaxf(acc[11] * inv, 0.f));
        *(float4*)(p) = v;
    }
}

// ---------------- Fallback fused kernel (ws too small for Q) ----------------

__global__ __launch_bounds__(256) void fused_kernel(
    const float* __restrict__ feat,
    const float* __restrict__ W,
    const int* __restrict__ offsets,
    const int* __restrict__ csr_src,
    float* __restrict__ out) {
    __shared__ __align__(16) float lds_w[FIN * FOUT];
    __shared__ __align__(16) float lds_t[NODE_ELEMS];

    const int n = blockIdx.x;
    const int tid = threadIdx.x;

    {
        const float4* w4 = (const float4*)W;
        float4* l4 = (float4*)lds_w;
        #pragma unroll
        for (int i = 0; i < 4; ++i) l4[tid + i * 256] = w4[tid + i * 256];
    }
    {
        const float4* f4 = (const float4*)(feat + (size_t)n * NODE_ELEMS);
        float4* l4 = (float4*)lds_t;
        #pragma unroll
        for (int i = 0; i < 3; ++i) l4[tid + i * 256] = f4[tid + i * 256];
    }
    __syncthreads();

    const int j = tid & 63;
    float wcol[64];
    #pragma unroll
    for (int k = 0; k < 64; ++k) wcol[k] = lds_w[k * 64 + j];

    float* outn = out + (size_t)n * NODE_OUT;

    #pragma unroll
    for (int i = 0; i < 12; ++i) {
        int r = (tid + i * 256) >> 6;
        const float4* m4 = (const float4*)(lds_t + r * 64);
        float s = 0.f;
        #pragma unroll
        for (int k4 = 0; k4 < 16; ++k4) {
            float4 m = m4[k4];
            s += m.x * wcol[4 * k4 + 0] + m.y * wcol[4 * k4 + 1] +
                 m.z * wcol[4 * k4 + 2] + m.w * wcol[4 * k4 + 3];
        }
        outn[r * OUT_ROW + j] = fmaxf(s, 0.f);
    }

    const int e0 = offsets[n], e1 = offsets[n + 1];
    float4 acc[3];
    #pragma unroll
    for (int i = 0; i < 3; ++i) acc[i] = make_float4(0.f, 0.f, 0.f, 0.f);
    for (int e = e0; e < e1; ++e) {
        int src = csr_src[e];
        const float4* f4 = (const float4*)(feat + (size_t)src * NODE_ELEMS);
        #pragma unroll
        for (int i = 0; i < 3; ++i) {
            float4 v = f4[tid + i * 256];
            acc[i].x += v.x; acc[i].y += v.y; acc[i].z += v.z; acc[i].w += v.w;
        }
    }
    const float inv = 1.0f / (float)((e1 - e0) > 1 ? (e1 - e0) : 1);

    __syncthreads();
    {
        float4* l4 = (float4*)lds_t;
        #pragma unroll
        for (int i = 0; i < 3; ++i) {
            float4 a = acc[i];
            a.x *= inv; a.y *= inv; a.z *= inv; a.w *= inv;
            l4[tid + i * 256] = a;
        }
    }
    __syncthreads();

    #pragma unroll
    for (int i = 0; i < 12; ++i) {
        int r = (tid + i * 256) >> 6;
        const float4* m4 = (const float4*)(lds_t + r * 64);
        float s = 0.f;
        #pragma unroll
        for (int k4 = 0; k4 < 16; ++k4) {
            float4 m = m4[k4];
            s += m.x * wcol[4 * k4 + 0] + m.y * wcol[4 * k4 + 1] +
                 m.z * wcol[4 * k4 + 2] + m.w * wcol[4 * k4 + 3];
        }
        outn[r * OUT_ROW + 64 + j] = fmaxf(s, 0.f);
    }
}

// ---------------- launch ----------------

extern "C" void kernel_launch(void* const* d_in, const int* in_sizes, int n_in,
                              void* d_out, int out_size, void* d_ws, size_t ws_size,
                              hipStream_t stream) {
    const float* feat = (const float*)d_in[0];
    const float* W    = (const float*)d_in[1];
    const int* edst   = (const int*)d_in[2];
    const int* esrc   = (const int*)d_in[3];
    float* out = (float*)d_out;

    int* counts  = (int*)d_ws;
    int* offsets = counts + N_NODES;          // N_NODES + 1
    int* cursor  = offsets + N_NODES + 1;
    int* csr_src = cursor + N_NODES;          // N_EDGES
    // bf16 Q buffer, 256B-aligned after the 55001 ints
    const size_t q_off = 220160;              // bytes
    const size_t q_bytes = (size_t)N_NODES * NODE_ELEMS * 2;  // 30.72 MB
    unsigned short* Q = (unsigned short*)((char*)d_ws + q_off);

    zero_counts_kernel<<<(N_NODES + 255) / 256, 256, 0, stream>>>(counts);
    hist_kernel<<<(N_EDGES + 255) / 256, 256, 0, stream>>>(edst, counts);
    scan_kernel<<<1, 1024, 0, stream>>>(counts, offsets, cursor);
    scatter_kernel<<<(N_EDGES + 255) / 256, 256, 0, stream>>>(edst, esrc, cursor, csr_src);

    if (ws_size >= q_off + q_bytes) {
        matmul_kernel<<<N_NODES, 256, 0, stream>>>(feat, W, out, Q);
        gather_kernel<<<N_NODES, 256, 0, stream>>>(Q, offsets, csr_src, out);
    } else {
        fused_kernel<<<N_NODES, 256, 0, stream>>>(feat, W, offsets, csr_src, out);
    }
}